// Round 1
// baseline (599.805 us; speedup 1.0000x reference)
//
#include <hip/hip_runtime.h>

// LSTM: B=2048, T=512, D=1, H=50, OUT=3, fp32.
// Mapping: one wave64 per batch element (2048 waves = 8/CU = 2/SIMD).
// Lane j owns hidden unit j (lanes 50..63 compute clamped duplicates, never read).
// W_hh rows for lane j's 4 gates held in 200 VGPRs for the whole kernel.
// h_k broadcast via v_readlane -> SGPR operand of v_fma_f32 (no LDS, no barriers
// in the scan: within-wave lockstep makes the recurrence race-free).

#define BB   2048
#define TT   512
#define HH   50

__device__ __forceinline__ float readlane_f(float v, int lane) {
    union { float f; int i; } u;
    u.f = v;
    u.i = __builtin_amdgcn_readlane(u.i, lane);
    return u.f;
}

__device__ __forceinline__ float fast_sigmoid(float x) {
    // 1 / (1 + e^-x);  v_exp_f32 computes 2^x
    float e = __builtin_amdgcn_exp2f(-1.4426950408889634f * x);
    return __builtin_amdgcn_rcpf(1.0f + e);
}

__device__ __forceinline__ float fast_tanh(float x) {
    // tanh(x) = 2*sigmoid(2x) - 1 ; saturates correctly via exp overflow->inf, rcp(inf)=0
    float e = __builtin_amdgcn_exp2f(-2.8853900817779268f * x);  // e^{-2x}
    return __builtin_amdgcn_rcpf(1.0f + e) * 2.0f - 1.0f;
}

__global__ __launch_bounds__(256, 2)
void lstm_scan_kernel(const float* __restrict__ x,
                      const float* __restrict__ W_ih,
                      const float* __restrict__ W_hh,
                      const float* __restrict__ b_ih,
                      const float* __restrict__ b_hh,
                      const float* __restrict__ fc_w,
                      const float* __restrict__ fc_b,
                      float* __restrict__ out) {
    __shared__ float xs[4 * TT];   // 4 waves/block, one x-row each (8 KB)

    const int tid  = threadIdx.x;
    const int wave = tid >> 6;
    const int lane = tid & 63;
    const int b0   = blockIdx.x * 4;
    const int b    = b0 + wave;

    // Stage this block's 4 x-rows into LDS (coalesced: 2048 floats / 256 threads)
    #pragma unroll
    for (int i = 0; i < 8; ++i) {
        int idx = i * 256 + tid;
        xs[idx] = x[b0 * TT + idx];
    }
    __syncthreads();

    const int j = (lane < HH) ? lane : (HH - 1);   // clamp idle lanes to valid rows

    // Recurrent weights into registers: w{g}[k] = W_hh[(g*H + j)*H + k]
    float w0[HH], w1[HH], w2[HH], w3[HH];
    #pragma unroll
    for (int k = 0; k < HH; ++k) {
        w0[k] = W_hh[(0 * HH + j) * HH + k];
        w1[k] = W_hh[(1 * HH + j) * HH + k];
        w2[k] = W_hh[(2 * HH + j) * HH + k];
        w3[k] = W_hh[(3 * HH + j) * HH + k];
    }
    // Input projection weights (D=1) and fused biases
    const float wi0 = W_ih[0 * HH + j];
    const float wi1 = W_ih[1 * HH + j];
    const float wi2 = W_ih[2 * HH + j];
    const float wi3 = W_ih[3 * HH + j];
    const float bs0 = b_ih[0 * HH + j] + b_hh[0 * HH + j];
    const float bs1 = b_ih[1 * HH + j] + b_hh[1 * HH + j];
    const float bs2 = b_ih[2 * HH + j] + b_hh[2 * HH + j];
    const float bs3 = b_ih[3 * HH + j] + b_hh[3 * HH + j];

    float h = 0.0f, c = 0.0f;
    const float* xrow = xs + wave * TT;

    #pragma unroll 1
    for (int t = 0; t < TT; ++t) {
        float xv = xrow[t];                 // uniform-address LDS broadcast
        float ai = fmaf(xv, wi0, bs0);
        float af = fmaf(xv, wi1, bs1);
        float ag = fmaf(xv, wi2, bs2);
        float ao = fmaf(xv, wi3, bs3);
        #pragma unroll
        for (int k = 0; k < HH; ++k) {
            float hk = readlane_f(h, k);    // SGPR broadcast of h[k]
            ai = fmaf(hk, w0[k], ai);
            af = fmaf(hk, w1[k], af);
            ag = fmaf(hk, w2[k], ag);
            ao = fmaf(hk, w3[k], ao);
        }
        float ig = fast_sigmoid(ai);
        float fg = fast_sigmoid(af);
        float gg = fast_tanh(ag);
        float og = fast_sigmoid(ao);
        c = fmaf(fg, c, ig * gg);
        h = og * fast_tanh(c);
    }

    // Epilogue: out[b][o] = sum_j h_j * fc_w[o][j] + fc_b[o]
    float hv = (lane < HH) ? h : 0.0f;
    float r0 = hv * fc_w[0 * HH + j];
    float r1 = hv * fc_w[1 * HH + j];
    float r2 = hv * fc_w[2 * HH + j];
    #pragma unroll
    for (int off = 32; off > 0; off >>= 1) {
        r0 += __shfl_down(r0, off, 64);
        r1 += __shfl_down(r1, off, 64);
        r2 += __shfl_down(r2, off, 64);
    }
    if (lane == 0) {
        out[b * 3 + 0] = r0 + fc_b[0];
        out[b * 3 + 1] = r1 + fc_b[1];
        out[b * 3 + 2] = r2 + fc_b[2];
    }
}

extern "C" void kernel_launch(void* const* d_in, const int* in_sizes, int n_in,
                              void* d_out, int out_size, void* d_ws, size_t ws_size,
                              hipStream_t stream) {
    const float* x    = (const float*)d_in[0];
    const float* W_ih = (const float*)d_in[1];
    const float* W_hh = (const float*)d_in[2];
    const float* b_ih = (const float*)d_in[3];
    const float* b_hh = (const float*)d_in[4];
    const float* fc_w = (const float*)d_in[5];
    const float* fc_b = (const float*)d_in[6];
    float* out = (float*)d_out;

    dim3 grid(BB / 4);   // 512 blocks, 4 waves (batch elements) per block
    dim3 block(256);
    lstm_scan_kernel<<<grid, block, 0, stream>>>(x, W_ih, W_hh, b_ih, b_hh,
                                                 fc_w, fc_b, out);
}

// Round 3
// 582.670 us; speedup vs baseline: 1.0294x; 1.0294x over previous
//
#include <hip/hip_runtime.h>

// LSTM: B=2048, T=512, D=1, H=50, OUT=3, fp32.
// Mapping: one wave64 per batch element (2048 waves = 8/CU = 2 waves/SIMD).
// Lane j owns hidden unit j. The 4 recurrent weight rows for unit j (200
// floats) are held in 200 NAMED scalar registers (macro-generated) so SROA
// must promote them; amdgpu_waves_per_eu(2,2) gives the allocator the full
// 256-VGPR budget so they stay in arch VGPRs (round-1 run allocated 112 VGPRs
// and shuffled weights through AGPRs -> +200 moves/step -> 2.2x slowdown).
// h_k broadcast via v_readlane -> SGPR operand of v_fma_f32. No barriers in
// the 512-step scan (within-wave lockstep).

#define BB   2048
#define TT   512
#define HH   50

__device__ __forceinline__ float readlane_f(float v, int lane) {
    union { float f; int i; } u;
    u.f = v;
    u.i = __builtin_amdgcn_readlane(u.i, lane);
    return u.f;
}

__device__ __forceinline__ float fast_sigmoid(float x) {
    float e = __builtin_amdgcn_exp2f(-1.4426950408889634f * x);
    return __builtin_amdgcn_rcpf(1.0f + e);
}

__device__ __forceinline__ float fast_tanh(float x) {
    float e = __builtin_amdgcn_exp2f(-2.8853900817779268f * x);  // e^{-2x}
    return __builtin_amdgcn_rcpf(1.0f + e) * 2.0f - 1.0f;
}

// Apply macro M to k = 0..49
#define REPK(M) \
  M(0)  M(1)  M(2)  M(3)  M(4)  M(5)  M(6)  M(7)  M(8)  M(9)  \
  M(10) M(11) M(12) M(13) M(14) M(15) M(16) M(17) M(18) M(19) \
  M(20) M(21) M(22) M(23) M(24) M(25) M(26) M(27) M(28) M(29) \
  M(30) M(31) M(32) M(33) M(34) M(35) M(36) M(37) M(38) M(39) \
  M(40) M(41) M(42) M(43) M(44) M(45) M(46) M(47) M(48) M(49)

__global__ __launch_bounds__(256)
__attribute__((amdgpu_waves_per_eu(2, 2)))
void lstm_scan_kernel(const float* __restrict__ x,
                      const float* __restrict__ W_ih,
                      const float* __restrict__ W_hh,
                      const float* __restrict__ b_ih,
                      const float* __restrict__ b_hh,
                      const float* __restrict__ fc_w,
                      const float* __restrict__ fc_b,
                      float* __restrict__ out) {
    __shared__ float xs[4 * TT];   // 4 waves/block, one x-row each (8 KB)

    const int tid  = threadIdx.x;
    const int wave = tid >> 6;
    const int lane = tid & 63;
    const int b0   = blockIdx.x * 4;
    const int b    = b0 + wave;

    // Stage this block's 4 x-rows into LDS (coalesced)
    #pragma unroll
    for (int i = 0; i < 8; ++i) {
        int idx = i * 256 + tid;
        xs[idx] = x[b0 * TT + idx];
    }
    __syncthreads();

    const int j = (lane < HH) ? lane : (HH - 1);   // clamp idle lanes

    // 200 named weight scalars: w{g}_{k} = W_hh[(g*H + j)*H + k].
    // k-consecutive addresses -> compiler merges into dwordx4 loads.
#define WDECL(k) \
    const float w0_##k = W_hh[(0 * HH + j) * HH + (k)]; \
    const float w1_##k = W_hh[(1 * HH + j) * HH + (k)]; \
    const float w2_##k = W_hh[(2 * HH + j) * HH + (k)]; \
    const float w3_##k = W_hh[(3 * HH + j) * HH + (k)];
    REPK(WDECL)
#undef WDECL

    const float wi0 = W_ih[0 * HH + j];
    const float wi1 = W_ih[1 * HH + j];
    const float wi2 = W_ih[2 * HH + j];
    const float wi3 = W_ih[3 * HH + j];
    const float bs0 = b_ih[0 * HH + j] + b_hh[0 * HH + j];
    const float bs1 = b_ih[1 * HH + j] + b_hh[1 * HH + j];
    const float bs2 = b_ih[2 * HH + j] + b_hh[2 * HH + j];
    const float bs3 = b_ih[3 * HH + j] + b_hh[3 * HH + j];

    float h = 0.0f, c = 0.0f;
    const float* xrow = xs + wave * TT;

    float xc = xrow[0];                  // software-pipelined x read
    #pragma unroll 1
    for (int t = 0; t < TT; ++t) {
        const float xn = xrow[(t + 1) & (TT - 1)];   // prefetch next step
        float ai = fmaf(xc, wi0, bs0);
        float af = fmaf(xc, wi1, bs1);
        float ag = fmaf(xc, wi2, bs2);
        float ao = fmaf(xc, wi3, bs3);
#define KSTEP(k) { \
        const float hk = readlane_f(h, k); \
        ai = fmaf(hk, w0_##k, ai); \
        af = fmaf(hk, w1_##k, af); \
        ag = fmaf(hk, w2_##k, ag); \
        ao = fmaf(hk, w3_##k, ao); }
        REPK(KSTEP)
#undef KSTEP
        const float ig = fast_sigmoid(ai);
        const float fg = fast_sigmoid(af);
        const float gg = fast_tanh(ag);
        const float og = fast_sigmoid(ao);
        c = fmaf(fg, c, ig * gg);
        h = og * fast_tanh(c);
        xc = xn;
    }

    // Epilogue: out[b][o] = sum_j h_j * fc_w[o][j] + fc_b[o]
    const float hv = (lane < HH) ? h : 0.0f;
    float r0 = hv * fc_w[0 * HH + j];
    float r1 = hv * fc_w[1 * HH + j];
    float r2 = hv * fc_w[2 * HH + j];
    #pragma unroll
    for (int off = 32; off > 0; off >>= 1) {
        r0 += __shfl_down(r0, off, 64);
        r1 += __shfl_down(r1, off, 64);
        r2 += __shfl_down(r2, off, 64);
    }
    if (lane == 0) {
        out[b * 3 + 0] = r0 + fc_b[0];
        out[b * 3 + 1] = r1 + fc_b[1];
        out[b * 3 + 2] = r2 + fc_b[2];
    }
}

extern "C" void kernel_launch(void* const* d_in, const int* in_sizes, int n_in,
                              void* d_out, int out_size, void* d_ws, size_t ws_size,
                              hipStream_t stream) {
    const float* x    = (const float*)d_in[0];
    const float* W_ih = (const float*)d_in[1];
    const float* W_hh = (const float*)d_in[2];
    const float* b_ih = (const float*)d_in[3];
    const float* b_hh = (const float*)d_in[4];
    const float* fc_w = (const float*)d_in[5];
    const float* fc_b = (const float*)d_in[6];
    float* out = (float*)d_out;

    dim3 grid(BB / 4);   // 512 blocks, 4 waves (batch elements) per block
    dim3 block(256);
    lstm_scan_kernel<<<grid, block, 0, stream>>>(x, W_ih, W_hh, b_ih, b_hh,
                                                 fc_w, fc_b, out);
}